// Round 4
// baseline (162.666 us; speedup 1.0000x reference)
//
#include <hip/hip_runtime.h>
#include <hip/hip_bf16.h>

#define Bsz 4
#define Ssz 2048
#define Dsz 512
#define Hsz 8
#define DKsz 64

typedef __bf16 bf16x8 __attribute__((ext_vector_type(8)));
typedef __bf16 bf16x4 __attribute__((ext_vector_type(4)));
typedef float f32x4 __attribute__((ext_vector_type(4)));

// chunk-swizzled element offset: 16B chunk c of a 64-elem (128B) row, XOR row&7
#define SWE(c, row) ((((c) ^ ((row) & 7)) * 8))

// ---------------------------------------------------------------------------
// cvt: x (4.19M fp32) + Wq|Wk|Wv (3 x 262144 fp32) -> bf16 in ws.
__global__ __launch_bounds__(256) void cvt_kernel(
    const float* __restrict__ x, const float* __restrict__ Wq,
    const float* __restrict__ Wk, const float* __restrict__ Wv,
    __bf16* __restrict__ xb, __bf16* __restrict__ Wb)
{
    const int i = blockIdx.x * 256 + threadIdx.x;   // float4 index
    const int XN4 = (Bsz * Ssz * Dsz) / 4;          // 1,048,576
    const float* src;
    __bf16* dst;
    int off;
    if (i < XN4) {
        src = x; dst = xb; off = i;
    } else {
        int j = i - XN4;                             // 0 .. 196607
        int w = j >> 16;                             // 0,1,2
        off = j & 65535;
        src = (w == 0) ? Wq : (w == 1) ? Wk : Wv;
        dst = Wb + (size_t)w * (Dsz * Dsz);
    }
    float4 v = ((const float4*)src)[off];
    __bf16 o[4] = {(__bf16)v.x, (__bf16)v.y, (__bf16)v.z, (__bf16)v.w};
    *(uint2*)(dst + (size_t)off * 4) = *(uint2*)o;
}

// ---------------------------------------------------------------------------
// qkv projection body. 128x128 tile, 4 waves (64x64 C-subtile each), BK=64,
// swizzled LDS, register prefetch, packed 8B epilogue stores.
// VM=false (Q/K): C = W-tile x x-tile  -> rows=e (in-lane), cols=s.
// VM=true  (V) : C = x-tile x W-tile  -> rows=s (in-lane), cols=e -> V^T.
template<bool VM>
__device__ __forceinline__ void qkv_body(
    const __bf16* __restrict__ xb, const __bf16* __restrict__ W,
    __bf16* __restrict__ dst, float scale)
{
    __shared__ __bf16 xs[128][64];
    __shared__ __bf16 wsh[128][64];

    const int tid  = threadIdx.x;
    const int lane = tid & 63;
    const int wave = tid >> 6;
    const int quad = lane >> 4;
    const int l16  = lane & 15;
    const int wm   = (wave & 1) * 64;
    const int wn   = (wave >> 1) * 64;

    const int tm = blockIdx.x * 128;      // x-row tile
    const int tn = blockIdx.y * 128;      // W-row tile

    const int srow = tid >> 1;            // 0..127
    const int c0   = (tid & 1) * 4;       // chunks c0..c0+3

    const __bf16* xg = xb + (size_t)(tm + srow) * Dsz;
    const __bf16* wg = W  + (size_t)(tn + srow) * Dsz;

    bf16x8 px[4], pw[4];
    #pragma unroll
    for (int i = 0; i < 4; ++i) {
        px[i] = *(const bf16x8*)(xg + (c0 + i) * 8);
        pw[i] = *(const bf16x8*)(wg + (c0 + i) * 8);
    }

    f32x4 acc[4][4];
    #pragma unroll
    for (int i = 0; i < 4; ++i)
        #pragma unroll
        for (int j = 0; j < 4; ++j) acc[i][j] = (f32x4){0.f, 0.f, 0.f, 0.f};

    for (int k0 = 0; k0 < Dsz; k0 += 64) {
        __syncthreads();
        #pragma unroll
        for (int i = 0; i < 4; ++i) {
            *(bf16x8*)&xs[srow][SWE(c0 + i, srow)]  = px[i];
            *(bf16x8*)&wsh[srow][SWE(c0 + i, srow)] = pw[i];
        }
        __syncthreads();
        if (k0 + 64 < Dsz) {
            #pragma unroll
            for (int i = 0; i < 4; ++i) {
                px[i] = *(const bf16x8*)(xg + k0 + 64 + (c0 + i) * 8);
                pw[i] = *(const bf16x8*)(wg + k0 + 64 + (c0 + i) * 8);
            }
        }

        #pragma unroll
        for (int kk = 0; kk < 2; ++kk) {
            bf16x8 fa[4], fb[4];
            #pragma unroll
            for (int mi = 0; mi < 4; ++mi) {
                const int row = wm + mi * 16 + l16;
                fa[mi] = VM ? *(const bf16x8*)&xs[row][SWE(kk * 4 + quad, row)]
                            : *(const bf16x8*)&wsh[row][SWE(kk * 4 + quad, row)];
            }
            #pragma unroll
            for (int ni = 0; ni < 4; ++ni) {
                const int row = wn + ni * 16 + l16;
                fb[ni] = VM ? *(const bf16x8*)&wsh[row][SWE(kk * 4 + quad, row)]
                            : *(const bf16x8*)&xs[row][SWE(kk * 4 + quad, row)];
            }
            #pragma unroll
            for (int mi = 0; mi < 4; ++mi)
                #pragma unroll
                for (int ni = 0; ni < 4; ++ni)
                    acc[mi][ni] = __builtin_amdgcn_mfma_f32_16x16x32_bf16(
                        fa[mi], fb[ni], acc[mi][ni], 0, 0, 0);
        }
    }

    if (!VM) {
        // rows = e (W-dim), in-lane regs r span 4 consecutive e -> 4 consecutive d
        #pragma unroll
        for (int mi = 0; mi < 4; ++mi) {
            const int e0 = tn + wm + mi * 16 + quad * 4;
            const int h = e0 >> 6, d0 = e0 & 63;
            #pragma unroll
            for (int ni = 0; ni < 4; ++ni) {
                const int sf = tm + wn + ni * 16 + l16;
                const int b = sf >> 11, s = sf & (Ssz - 1);
                bf16x4 p;
                #pragma unroll
                for (int r = 0; r < 4; ++r) p[r] = (__bf16)(acc[mi][ni][r] * scale);
                *(bf16x4*)&dst[((((size_t)(b * Hsz + h) * Ssz + s)) << 6) + d0] = p;
            }
        }
    } else {
        // rows = s, in-lane regs r span 4 consecutive s -> V^T packed stores
        #pragma unroll
        for (int mi = 0; mi < 4; ++mi) {
            const int sf0 = tm + wm + mi * 16 + quad * 4;
            const int b = sf0 >> 11, s0 = sf0 & (Ssz - 1);
            #pragma unroll
            for (int ni = 0; ni < 4; ++ni) {
                const int e = tn + wn + ni * 16 + l16;
                const int h = e >> 6, d = e & 63;
                bf16x4 p;
                #pragma unroll
                for (int r = 0; r < 4; ++r) p[r] = (__bf16)acc[mi][ni][r];
                *(bf16x4*)&dst[(((size_t)(b * Hsz + h) * DKsz + d) << 11) + s0] = p;
            }
        }
    }
}

__global__ __launch_bounds__(256, 2) void qkv_qk_kernel(
    const __bf16* __restrict__ xb, const __bf16* __restrict__ Wb,
    __bf16* __restrict__ Qo, __bf16* __restrict__ Ko)
{
    const int which = blockIdx.z;   // 0=Q 1=K
    const float qscale = 0.125f * 1.44269504088896340736f;
    qkv_body<false>(xb, Wb + (size_t)which * (Dsz * Dsz),
                    which == 0 ? Qo : Ko, which == 0 ? qscale : 1.0f);
}

__global__ __launch_bounds__(256, 2) void qkv_v_kernel(
    const __bf16* __restrict__ xb, const __bf16* __restrict__ Wb,
    __bf16* __restrict__ Vo)
{
    qkv_body<true>(xb, Wb + (size_t)2 * (Dsz * Dsz), Vo, 1.0f);
}

// ---------------------------------------------------------------------------
// Flash-style attention, exp2 (scale folded into Q), no max-subtraction.
// Block: 4 waves x 4 q-subtiles = 256 q-rows of one (b,h). Swizzled LDS,
// swapped-operand PV (O^T in regs -> f32x4 stores, per-lane row-sums).
__global__ __launch_bounds__(256, 1) void attn_kernel(
    const __bf16* __restrict__ Q, const __bf16* __restrict__ K,
    const __bf16* __restrict__ VT, float* __restrict__ out)
{
    __shared__ __bf16 ks[64][64];        // K[s_local][dk], swizzled chunks
    __shared__ __bf16 vs[64][64];        // V^T[dk][s_local], swizzled chunks
    __shared__ __bf16 ps[4][16][64];     // per-wave P (reused across qs)

    const int tid  = threadIdx.x;
    const int lane = tid & 63;
    const int wave = tid >> 6;
    const int quad = lane >> 4;
    const int l16  = lane & 15;

    const int bh = blockIdx.x;           // all q-blocks of a bh share an XCD L2
    const int qt = blockIdx.y;
    const int b  = bh >> 3;
    const int h  = bh & 7;

    const __bf16* Qb = Q  + (size_t)bh * Ssz * DKsz;
    const __bf16* Kb = K  + (size_t)bh * Ssz * DKsz;
    const __bf16* Vb = VT + (size_t)bh * DKsz * Ssz;

    bf16x8 qf[4][2];
    #pragma unroll
    for (int qs = 0; qs < 4; ++qs) {
        const __bf16* qrow = Qb + (size_t)(qt * 256 + wave * 64 + qs * 16 + l16) * DKsz;
        qf[qs][0] = *(const bf16x8*)(qrow + quad * 8);
        qf[qs][1] = *(const bf16x8*)(qrow + 32 + quad * 8);
    }

    bf16x8 ones;
    #pragma unroll
    for (int i = 0; i < 8; ++i) ones[i] = (__bf16)1.0f;

    f32x4 oacc[4][4];
    #pragma unroll
    for (int qs = 0; qs < 4; ++qs)
        #pragma unroll
        for (int i = 0; i < 4; ++i) oacc[qs][i] = (f32x4){0.f, 0.f, 0.f, 0.f};
    f32x4 lacc[4];
    #pragma unroll
    for (int qs = 0; qs < 4; ++qs) lacc[qs] = (f32x4){0.f, 0.f, 0.f, 0.f};

    const int srow = tid >> 2;           // 0..63
    const int c0   = tid & 3;            // chunks c0, c0+4

    bf16x8 pk0 = *(const bf16x8*)(Kb + (size_t)srow * DKsz + c0 * 8);
    bf16x8 pk1 = *(const bf16x8*)(Kb + (size_t)srow * DKsz + (c0 + 4) * 8);
    bf16x8 pv0 = *(const bf16x8*)(Vb + (size_t)srow * Ssz + c0 * 8);
    bf16x8 pv1 = *(const bf16x8*)(Vb + (size_t)srow * Ssz + (c0 + 4) * 8);

    for (int kb = 0; kb < Ssz; kb += 64) {
        __syncthreads();
        *(bf16x8*)&ks[srow][SWE(c0, srow)]     = pk0;
        *(bf16x8*)&ks[srow][SWE(c0 + 4, srow)] = pk1;
        *(bf16x8*)&vs[srow][SWE(c0, srow)]     = pv0;
        *(bf16x8*)&vs[srow][SWE(c0 + 4, srow)] = pv1;
        __syncthreads();

        if (kb + 64 < Ssz) {
            pk0 = *(const bf16x8*)(Kb + (size_t)(kb + 64 + srow) * DKsz + c0 * 8);
            pk1 = *(const bf16x8*)(Kb + (size_t)(kb + 64 + srow) * DKsz + (c0 + 4) * 8);
            pv0 = *(const bf16x8*)(Vb + (size_t)srow * Ssz + kb + 64 + c0 * 8);
            pv1 = *(const bf16x8*)(Vb + (size_t)srow * Ssz + kb + 64 + (c0 + 4) * 8);
        }

        // read K and V tiles once into registers
        bf16x8 kf[2][4], vf[2][4];
        #pragma unroll
        for (int kk = 0; kk < 2; ++kk)
            #pragma unroll
            for (int ns = 0; ns < 4; ++ns) {
                const int row = ns * 16 + l16;
                kf[kk][ns] = *(const bf16x8*)&ks[row][SWE(kk * 4 + quad, row)];
                vf[kk][ns] = *(const bf16x8*)&vs[row][SWE(kk * 4 + quad, row)];
            }

        #pragma unroll
        for (int qs = 0; qs < 4; ++qs) {
            // S = Q K^T (C: row=q-local, col=s-local)
            f32x4 sacc[4];
            #pragma unroll
            for (int ns = 0; ns < 4; ++ns) {
                sacc[ns] = (f32x4){0.f, 0.f, 0.f, 0.f};
                sacc[ns] = __builtin_amdgcn_mfma_f32_16x16x32_bf16(qf[qs][0], kf[0][ns], sacc[ns], 0, 0, 0);
                sacc[ns] = __builtin_amdgcn_mfma_f32_16x16x32_bf16(qf[qs][1], kf[1][ns], sacc[ns], 0, 0, 0);
            }
            // P = exp2(S) -> per-wave LDS (C-layout -> frag layout)
            #pragma unroll
            for (int ns = 0; ns < 4; ++ns) {
                const int c = ns * 2 + (l16 >> 3);
                #pragma unroll
                for (int r = 0; r < 4; ++r) {
                    const int prow = quad * 4 + r;
                    ps[wave][prow][SWE(c, prow) + (l16 & 7)] =
                        (__bf16)__builtin_amdgcn_exp2f(sacc[ns][r]);
                }
            }
            bf16x8 af0 = *(const bf16x8*)&ps[wave][l16][SWE(quad, l16)];
            bf16x8 af1 = *(const bf16x8*)&ps[wave][l16][SWE(4 + quad, l16)];
            // O^T += V^T P^T : rows=d (in-lane), cols=q (l16)
            #pragma unroll
            for (int ns = 0; ns < 4; ++ns) {
                oacc[qs][ns] = __builtin_amdgcn_mfma_f32_16x16x32_bf16(vf[0][ns], af0, oacc[qs][ns], 0, 0, 0);
                oacc[qs][ns] = __builtin_amdgcn_mfma_f32_16x16x32_bf16(vf[1][ns], af1, oacc[qs][ns], 0, 0, 0);
            }
            lacc[qs] = __builtin_amdgcn_mfma_f32_16x16x32_bf16(ones, af0, lacc[qs], 0, 0, 0);
            lacc[qs] = __builtin_amdgcn_mfma_f32_16x16x32_bf16(ones, af1, lacc[qs], 0, 0, 0);
        }
    }

    // epilogue: per-lane row-sum (col=q=l16), f32x4 stores along d
    #pragma unroll
    for (int qs = 0; qs < 4; ++qs) {
        const float linv = 1.f / (lacc[qs][0] + 1e-8f);
        const int q = qt * 256 + wave * 64 + qs * 16 + l16;
        float* obase = out + ((size_t)b * Ssz + q) * Dsz + h * DKsz;
        #pragma unroll
        for (int ns = 0; ns < 4; ++ns) {
            f32x4 o = oacc[qs][ns] * linv;
            *(f32x4*)(obase + ns * 16 + quad * 4) = o;
        }
    }
}

extern "C" void kernel_launch(void* const* d_in, const int* in_sizes, int n_in,
                              void* d_out, int out_size, void* d_ws, size_t ws_size,
                              hipStream_t stream) {
    const float* x  = (const float*)d_in[0];
    const float* Wq = (const float*)d_in[1];
    const float* Wk = (const float*)d_in[2];
    const float* Wv = (const float*)d_in[3];
    float* out = (float*)d_out;

    const size_t per = (size_t)Bsz * Hsz * Ssz * DKsz;  // 4,194,304 elems
    __bf16* Qw  = (__bf16*)d_ws;
    __bf16* Kw  = Qw + per;
    __bf16* VTw = Kw + per;
    __bf16* xb  = VTw + per;
    __bf16* Wb  = xb + per;                              // 786,432 elems

    cvt_kernel<<<4864, 256, 0, stream>>>(x, Wq, Wk, Wv, xb, Wb);
    qkv_qk_kernel<<<dim3((Bsz * Ssz) / 128, Dsz / 128, 2), 256, 0, stream>>>(xb, Wb, Qw, Kw);
    qkv_v_kernel<<<dim3((Bsz * Ssz) / 128, Dsz / 128), 256, 0, stream>>>(xb, Wb, VTw);
    attn_kernel<<<dim3(Bsz * Hsz, Ssz / 256), 256, 0, stream>>>(Qw, Kw, VTw, out);
}